// Round 13
// baseline (307.373 us; speedup 1.0000x reference)
//
#include <hip/hip_runtime.h>
#include <hip/hip_bf16.h>

#define BB 8
#define NN 1024
#define EE 16384
#define FF 96
#define FE 32
#define NH 12
#define DD 8
#define KM 224   // 2F + Fe
#define KX 192   // 2F
#define TE 64    // rows per edge GEMM tile
#define TN 16    // rows per node-side GEMM tile (R13: small grids were the
                 // bottleneck — 64-row tiles gave out=128 blocks on 256 CUs)
#define BK 32    // K chunk

#if __has_builtin(__builtin_amdgcn_exp2f)
#define EXP2(x) __builtin_amdgcn_exp2f(x)
#else
#define EXP2(x) exp2f(x)
#endif

typedef _Float16 h2 __attribute__((ext_vector_type(2)));
typedef float    f2 __attribute__((ext_vector_type(2)));

// fdot2: c + a.x*b.x + a.y*b.y with f32 accumulate (v_dot2_f32_f16).
__device__ __forceinline__ float fdot2(h2 a, h2 b, float c){
#if __has_builtin(__builtin_amdgcn_fdot2)
    return __builtin_amdgcn_fdot2(a, b, c, false);
#else
    return c + (float)a[0]*(float)b[0] + (float)a[1]*(float)b[1];
#endif
}

// Packed fp32 FMA: acc = a*b + acc on both halves (v_pk_fma_f32, VOP3P).
// R11 lesson: WIN in attn (exp2-chain loop; VGPR 56->32, occ 32->47%,
// -6.3 µs). REGRESSION in GEMM kernels (+19 µs): the opaque asm blocks
// ds_read scheduling and adds a v_mov broadcast. Use in attn ONLY.
__device__ __forceinline__ void pk_fma(f2& acc, f2 a, f2 b){
    asm("v_pk_fma_f32 %0, %1, %2, %0" : "+v"(acc) : "v"(a), "v"(b));
}

__device__ __forceinline__ float gelu_erf(float x){
    return 0.5f * x * (1.0f + erff(x * 0.70710678118654752f));
}

__device__ __forceinline__ int load_idx(const int* __restrict__ p, int i){
    int v = p[i];
    if (!((unsigned)v < 1024u)) v = (int)__int_as_float(v);
    return min(max(v, 0), NN-1);
}

// ---------------- CSR build: histogram + FUSED passthrough outputs ----------
// NOTE (R7): do NOT replace the CSR subsystem with fused fp32 atomicAdd into
// agg — device-scope atomics bypass the per-XCD L2 (not cross-coherent):
// measured 344 MB WRITE_SIZE and a 269 µs edge kernel. CSR+gather is ~10x
// cheaper.
__global__ __launch_bounds__(256) void hist_kernel(
    const int* __restrict__ edges, int* __restrict__ cnt,
    const float* __restrict__ ew, const float* __restrict__ ed,
    float* __restrict__ o_edges, float* __restrict__ o_ew, float* __restrict__ o_ed)
{
    const int i = blockIdx.x*blockDim.x + threadIdx.x;
    if (i < BB*EE){
        const int b = i >> 14;
        const int dst = load_idx(edges, 2*i+1);
        atomicAdd(&cnt[b*NN + dst], 1);
    }
    const int NE2 = BB*EE*2;
    const int NW  = BB*EE;
    if (i < NE2)                 o_edges[i] = (float)load_idx(edges, i);
    else if (i < NE2+NW)         o_ew[i-NE2] = ew[i-NE2];
    else if (i < NE2+NW+NE2)     o_ed[i-NE2-NW] = ed[i-NE2-NW];
}

// ---------------- CSR build: per-batch exclusive scan (N=1024) ----------------
__global__ __launch_bounds__(1024) void scan_kernel(
    const int* __restrict__ cnt, int* __restrict__ rowstart, int* __restrict__ cursor)
{
    const int b = blockIdx.x;
    const int t = threadIdx.x;
    __shared__ int s[NN];
    const int v = cnt[b*NN + t];
    s[t] = v;
    __syncthreads();
    for (int off = 1; off < NN; off <<= 1){
        int u = (t >= off) ? s[t-off] : 0;
        __syncthreads();
        s[t] += u;
        __syncthreads();
    }
    const int ex = s[t] - v + b*EE;     // exclusive, offset by batch base
    rowstart[b*NN + t] = ex;
    cursor[b*NN + t]   = ex;
}

// ---------------- CSR build: scatter edge ids ----------------
__global__ __launch_bounds__(256) void scatter_kernel(
    const int* __restrict__ edges, int* __restrict__ cursor, int* __restrict__ elist)
{
    const int i = blockIdx.x*blockDim.x + threadIdx.x;   // global edge id
    if (i < BB*EE){
        const int b = i >> 14;
        const int dst = load_idx(edges, 2*i+1);
        const int pos = atomicAdd(&cursor[b*NN + dst], 1);
        elist[pos] = i;
    }
}

// ---------------- Kernel 0: node projections P1 = nodes@Wm1, P2 = nodes@Wm2 ----
// R13: 16-row tiles -> grid (512,2)=1024 blocks (was 256: latency-bound,
// most CUs idle). 256 thr = 16 rows x 16 col-groups; 1 row x 6 cols/thread.
__global__ __launch_bounds__(256) void node_proj_kernel(
    const float* __restrict__ nodes, const float* __restrict__ Wm,
    float* __restrict__ P1, float* __restrict__ P2)
{
    const int rt  = blockIdx.x;          // 512 row tiles of 16
    const int m   = blockIdx.y;          // 0: src-proj, 1: dst-proj
    const int tid = threadIdx.x;
    const int tx  = tid & 15;
    const int ty  = tid >> 4;
    const int r0  = rt * TN;

    const float* W = Wm + (size_t)(m ? FF : 0) * FF;   // rows [0,96) or [96,192)
    float* out     = m ? P2 : P1;

    __shared__ float Xs[TN][BK+2];
    __shared__ float Ws[BK][FF];

    float acc[6];
    #pragma unroll
    for (int c=0;c<6;++c) acc[c] = 0.f;

    for (int c = 0; c < 3; ++c){
        __syncthreads();
        {
            const float4* src = (const float4*)(W + (size_t)c*BK*FF);
            float4* dst = (float4*)&Ws[0][0];
            dst[tid      ] = src[tid      ];
            dst[tid + 256] = src[tid + 256];
            dst[tid + 512] = src[tid + 512];
        }
        {
            const float* rp = nodes + (size_t)(r0 + ty)*FF + c*BK;
            *(float2*)&Xs[ty][tx*2] = *(const float2*)(rp + tx*2);
        }
        __syncthreads();
        #pragma unroll 8
        for (int kk = 0; kk < BK; ++kk){
            float2 w01 = *(const float2*)&Ws[kk][6*tx    ];
            float2 w23 = *(const float2*)&Ws[kk][6*tx + 2];
            float2 w45 = *(const float2*)&Ws[kk][6*tx + 4];
            const float xv = Xs[ty][kk];
            acc[0] += xv*w01.x;  acc[1] += xv*w01.y;
            acc[2] += xv*w23.x;  acc[3] += xv*w23.y;
            acc[4] += xv*w45.x;  acc[5] += xv*w45.y;
        }
    }

    float* __restrict__ orow = out + (size_t)(r0 + ty)*FF + 6*tx;
    #pragma unroll
    for (int jj=0; jj<6; ++jj) orow[jj] = acc[jj];
}

// ---------------- Kernel 1: edge messages (K=32 GEMM + gather-add epilogue) ----
// acc = ef @ Wm3; epilogue adds P1[src] + P2[dst] + bm, then GELU + LN +
// edge-weight scale. TE=64 rows -> 2048 blocks (already grid-saturated).
__global__ __launch_bounds__(256) void edge_msg2_kernel(
    const float* __restrict__ P1, const float* __restrict__ P2,
    const float* __restrict__ ef,
    const int*  __restrict__ edges, const float* __restrict__ ew,
    const float* __restrict__ Wm, const float* __restrict__ bm,
    const float* __restrict__ gm, const float* __restrict__ betam,
    float* __restrict__ wm_out)
{
    const int bid = blockIdx.x;
    const int tid = threadIdx.x;
    const int tx  = tid & 15;
    const int ty  = tid >> 4;
    const int be0 = bid * TE;
    const int b   = be0 >> 14;

    __shared__ float Xs[TE][BK+4];
    __shared__ float Ws[BK][FF];
    __shared__ int   eidx[TE*2];
    __shared__ float ewS[TE];
    __shared__ float bmS[FF], gmS[FF], betamS[FF];

    if (tid < TE*2){
        int v = edges[(size_t)be0*2 + tid];
        if (!((unsigned)v < 1024u)) v = (int)__int_as_float(v);
        eidx[tid] = min(max(v, 0), NN-1);
    }
    if (tid < TE) ewS[tid] = ew[be0 + tid];
    if (tid < FF){ bmS[tid] = bm[tid]; gmS[tid] = gm[tid]; betamS[tid] = betam[tid]; }

    float acc[4][6];
    #pragma unroll
    for (int a=0;a<4;++a)
        #pragma unroll
        for (int c=0;c<6;++c) acc[a][c] = 0.f;

    const int e_st = tid >> 2;
    const int kk0  = (tid & 3) * 8;

    // ---- single K=32 chunk: ef @ Wm[192:224] ----
    {
        const float4* src = (const float4*)(Wm + (size_t)KX*FF);
        float4* dst = (float4*)&Ws[0][0];
        dst[tid      ] = src[tid      ];
        dst[tid + 256] = src[tid + 256];
        dst[tid + 512] = src[tid + 512];
    }
    {
        const float* rp = ef + (size_t)(be0 + e_st)*FE;
        *(float4*)&Xs[e_st][kk0    ] = *(const float4*)(rp + kk0);
        *(float4*)&Xs[e_st][kk0 + 4] = *(const float4*)(rp + kk0 + 4);
    }
    __syncthreads();
    #pragma unroll 4
    for (int kk = 0; kk < BK; ++kk){
        float2 w01 = *(const float2*)&Ws[kk][6*tx    ];
        float2 w23 = *(const float2*)&Ws[kk][6*tx + 2];
        float2 w45 = *(const float2*)&Ws[kk][6*tx + 4];
        float xv[4];
        #pragma unroll
        for (int ei=0; ei<4; ++ei) xv[ei] = Xs[ty + 16*ei][kk];
        #pragma unroll
        for (int ei=0; ei<4; ++ei){
            acc[ei][0] += xv[ei]*w01.x;  acc[ei][1] += xv[ei]*w01.y;
            acc[ei][2] += xv[ei]*w23.x;  acc[ei][3] += xv[ei]*w23.y;
            acc[ei][4] += xv[ei]*w45.x;  acc[ei][5] += xv[ei]*w45.y;
        }
    }

    // ---- prefetch node-projection gathers for all 4 rows (hide L2 latency) ----
    float add[4][6];
    #pragma unroll
    for (int ei = 0; ei < 4; ++ei){
        const int el = ty + 16*ei;
        const int sn = eidx[2*el];
        const int dn = eidx[2*el+1];
        const float2* p1 = (const float2*)(P1 + (size_t)(b*NN + sn)*FF + 6*tx);
        const float2* p2 = (const float2*)(P2 + (size_t)(b*NN + dn)*FF + 6*tx);
        const float2 a0 = p1[0], a1 = p1[1], a2 = p1[2];
        const float2 b0 = p2[0], b1 = p2[1], b2 = p2[2];
        add[ei][0] = a0.x + b0.x;  add[ei][1] = a0.y + b0.y;
        add[ei][2] = a1.x + b1.x;  add[ei][3] = a1.y + b1.y;
        add[ei][4] = a2.x + b2.x;  add[ei][5] = a2.y + b2.y;
    }

    #pragma unroll
    for (int ei = 0; ei < 4; ++ei){
        const int el = ty + 16*ei;
        float h[6]; float psum = 0.f;
        #pragma unroll
        for (int jj=0; jj<6; ++jj){
            h[jj] = gelu_erf(acc[ei][jj] + add[ei][jj] + bmS[6*tx + jj]);
            psum += h[jj];
        }
        #pragma unroll
        for (int m=1; m<16; m<<=1) psum += __shfl_xor(psum, m, 16);
        const float mu = psum * (1.f/FF);
        float vsum = 0.f;
        #pragma unroll
        for (int jj=0; jj<6; ++jj){ float d = h[jj]-mu; vsum += d*d; }
        #pragma unroll
        for (int m=1; m<16; m<<=1) vsum += __shfl_xor(vsum, m, 16);
        const float rstd = rsqrtf(vsum*(1.f/FF) + 1e-3f);

        const float w = ewS[el];
        float* __restrict__ wrow = wm_out + (size_t)(be0 + el)*FF + 6*tx;
        #pragma unroll
        for (int jj=0; jj<6; ++jj)
            wrow[jj] = ((h[jj]-mu)*rstd*gmS[6*tx+jj] + betamS[6*tx+jj]) * w;
    }
}

// ---------------- Kernel 1b: CSR gather -> agg ----------------
__global__ __launch_bounds__(96) void gather_kernel(
    const float* __restrict__ wm_out, const float* __restrict__ ed,
    const int* __restrict__ elist, const int* __restrict__ rowstart,
    const int* __restrict__ cnt, float* __restrict__ agg)
{
    const int bn = blockIdx.x;       // b*N + n
    const int t  = threadIdx.x;      // 96
    const int beg = rowstart[bn];
    const int num = cnt[bn];
    float sum = 0.f;
    for (int i = 0; i < num; ++i){
        const int be = elist[beg + i];
        const float coeff = ed[2*(size_t)be + 1];
        sum += wm_out[(size_t)be*FF + t] * coeff;
    }
    agg[(size_t)bn*FF + t] = sum;
}

// ---------------- Kernel 2: QKVG projections (tiled GEMM) ----------------
// R13: 16-row tiles -> grid (512,4)=2048 blocks (was 512). K (m==1)
// written f16 for attn's v_dot2_f32_f16 path (R8).
__global__ __launch_bounds__(256) void qkvg_kernel(
    const float* __restrict__ nodes, const float* __restrict__ agg,
    const float* __restrict__ Wq, const float* __restrict__ bq,
    const float* __restrict__ Wk, const float* __restrict__ bk,
    const float* __restrict__ Wv, const float* __restrict__ bv,
    const float* __restrict__ Wg, const float* __restrict__ bg,
    float* __restrict__ qo, _Float16* __restrict__ ko_h,
    float* __restrict__ vo, float* __restrict__ go)
{
    const int rt  = blockIdx.x;          // 512 row tiles of 16
    const int m   = blockIdx.y;          // 0..3
    const int tid = threadIdx.x;
    const int tx  = tid & 15;
    const int ty  = tid >> 4;
    const int r0  = rt * TN;

    const float* W    = (m==0)?Wq:(m==1)?Wk:(m==2)?Wv:Wg;
    const float* bias = (m==0)?bq:(m==1)?bk:(m==2)?bv:bg;
    float* out        = (m==0)?qo:(m==2)?vo:go;   // m==1 -> ko_h (f16 path)

    __shared__ float Xs[TN][BK+2];
    __shared__ float Ws[BK][FF];
    __shared__ float bS[FF];
    if (tid < FF) bS[tid] = bias[tid];

    float acc[6];
    #pragma unroll
    for (int c=0;c<6;++c) acc[c] = 0.f;

    for (int c = 0; c < 6; ++c){
        __syncthreads();
        {
            const float4* src = (const float4*)(W + (size_t)c*BK*FF);
            float4* dst = (float4*)&Ws[0][0];
            dst[tid      ] = src[tid      ];
            dst[tid + 256] = src[tid + 256];
            dst[tid + 512] = src[tid + 512];
        }
        {
            const float* rp = (c < 3)
                ? nodes + (size_t)(r0 + ty)*FF + c*BK
                : agg   + (size_t)(r0 + ty)*FF + (c-3)*BK;
            *(float2*)&Xs[ty][tx*2] = *(const float2*)(rp + tx*2);
        }
        __syncthreads();
        #pragma unroll 8
        for (int kk = 0; kk < BK; ++kk){
            float2 w01 = *(const float2*)&Ws[kk][6*tx    ];
            float2 w23 = *(const float2*)&Ws[kk][6*tx + 2];
            float2 w45 = *(const float2*)&Ws[kk][6*tx + 4];
            const float xv = Xs[ty][kk];
            acc[0] += xv*w01.x;  acc[1] += xv*w01.y;
            acc[2] += xv*w23.x;  acc[3] += xv*w23.y;
            acc[4] += xv*w45.x;  acc[5] += xv*w45.y;
        }
    }

    if (m == 1){
        _Float16* __restrict__ orow = ko_h + (size_t)(r0 + ty)*FF + 6*tx;
        #pragma unroll
        for (int jj=0; jj<6; ++jj) orow[jj] = (_Float16)(acc[jj] + bS[6*tx + jj]);
    } else {
        float* __restrict__ orow = out + (size_t)(r0 + ty)*FF + 6*tx;
        #pragma unroll
        for (int jj=0; jj<6; ++jj) orow[jj] = acc[jj] + bS[6*tx + jj];
    }
}

// ---------------- Kernel 3: gated attention (LDS-staged flash) ----------
// block = 256 thr = 4 waves per (b, h, 64-row q-tile). R2 lane decomp
// (1 q-row/lane, 16 rows x 4 key-streams) + exp2 rebase + fdot2 QK (R9)
// + -m-seeded dot chain + max3 group max (R10) + pk_fma PV (R11: 67.3 µs,
// VGPR 32, occ 47%) + single 8 KB LDS buffer with register prefetch.
// ~16 issue slots per (key,lane) — near the floor for this inst mix.
// att MAY alias g: final phase reads g then writes att from same thread.
__global__ __launch_bounds__(256) void attn_kernel(
    const float* __restrict__ q, const _Float16* __restrict__ kh,
    const float* __restrict__ v, const float* g,
    float* att)
{
    const int blk = blockIdx.x;
    const int qt = blk & 15;              // N/64 = 16 tiles
    const int h  = (blk >> 4) % NH;
    const int b  = blk / (16*NH);
    const int tid  = threadIdx.x;
    const int lane = tid & 63;
    const int w    = tid >> 6;            // wave id 0..3
    const int r    = lane & 15;           // row within wave
    const int s    = lane >> 4;           // key stream 0..3
    const int qrow = qt*64 + w*16 + r;
    const size_t base = (size_t)(b*NN)*FF + h*DD;

    __shared__ _Float16 Ks[128][8];       // 16 B rows (2 KB): 1 b128 = whole K row
    __shared__ float    Vs[128][12];      // 48 B rows (6 KB), conflict-free

    // Q -> f16 pairs, pre-scaled by log2(e)/sqrt(8) for the exp2 softmax
    h2 qh[4];
    {
        const float* qp = q + base + (size_t)qrow*FF;
        #pragma unroll
        for (int i=0;i<4;++i){
            qh[i][0] = (_Float16)(qp[2*i  ] * 0.51010300101462254f);
            qh[i][1] = (_Float16)(qp[2*i+1] * 0.51010300101462254f);
        }
    }

    // mneg = -m (running max, log2 domain), m starts at 0 (R10).
    float mneg = 0.f, l = 0.f;
    f2 o01 = (f2){0.f,0.f}, o23 = (f2){0.f,0.f};
    f2 o45 = (f2){0.f,0.f}, o67 = (f2){0.f,0.f};

    const int skey  = tid >> 1;           // staging: 2 threads per key
    const int half8 = (tid & 1) * 4;      // K: halfs 0-3 / 4-7 ; V: floats 0-3 / 4-7

    // prologue: fetch chunk 0 into regs (K row = 8 B per thread, V = 16 B)
    float2 kreg = *(const float2*)(kh + base + (size_t)skey*FF + half8);
    float4 vreg = *(const float4*)(v  + base + (size_t)skey*FF + half8);

    for (int t = 0; t < 8; ++t){
        // write staged regs (waits vmcnt for kreg/vreg only)
        *(float2*)&Ks[skey][half8] = kreg;
        *(float4*)&Vs[skey][half8] = vreg;
        __syncthreads();
        // issue next chunk's loads NOW; latency hides under compute below
        if (t < 7){
            kreg = *(const float2*)(kh + base + (size_t)((t+1)*128 + skey)*FF + half8);
            vreg = *(const float4*)(v  + base + (size_t)((t+1)*128 + skey)*FF + half8);
        }
        #pragma unroll
        for (int gidx = 0; gidx < 4; ++gidx){
            // pass 1: 8 score dots, chain seeded with -m (already subtracted)
            float sc[8];
            #pragma unroll
            for (int jj = 0; jj < 8; ++jj){
                const int key = 32*gidx + 4*jj + s;
                float4 kraw = *(const float4*)&Ks[key][0];   // 8 halfs
                const h2* kp = (const h2*)&kraw;
                sc[jj] = fdot2(qh[3], kp[3],
                         fdot2(qh[2], kp[2],
                         fdot2(qh[1], kp[1],
                         fdot2(qh[0], kp[0], mneg))));
            }
            // group max via max3-shaped nests (v_max3_f32) + rare rescale
            const float t0 = fmaxf(fmaxf(sc[0], sc[1]), sc[2]);
            const float t1 = fmaxf(fmaxf(sc[3], sc[4]), sc[5]);
            const float t2 = fmaxf(fmaxf(sc[6], sc[7]), t0);
            const float gmax = fmaxf(t1, t2);     // = max(sc[0..7]) (rel. to m)
            if (gmax > 11.5f){
                const float c = EXP2(-gmax);
                l *= c;
                o01[0]*=c; o01[1]*=c; o23[0]*=c; o23[1]*=c;
                o45[0]*=c; o45[1]*=c; o67[0]*=c; o67[1]*=c;
                mneg -= gmax;
                #pragma unroll
                for (int jj=0;jj<8;++jj) sc[jj] -= gmax;
            }
            // pass 2: exp2 + packed PV accumulate (v_pk_fma_f32)
            #pragma unroll
            for (int jj = 0; jj < 8; ++jj){
                const int key = 32*gidx + 4*jj + s;
                float4 v0 = *(const float4*)&Vs[key][0];
                float4 v1 = *(const float4*)&Vs[key][4];
                const f2* va = (const f2*)&v0;
                const f2* vb = (const f2*)&v1;
                const float p = EXP2(sc[jj]);
                l += p;
                f2 p2 = (f2){p, p};
                pk_fma(o01, p2, va[0]);
                pk_fma(o23, p2, va[1]);
                pk_fma(o45, p2, vb[0]);
                pk_fma(o67, p2, vb[1]);
            }
        }
        if (t < 7) __syncthreads();       // all reads done before overwrite
    }

    // unpack pairs for the cross-stream merge
    float o[DD];
    o[0]=o01[0]; o[1]=o01[1]; o[2]=o23[0]; o[3]=o23[1];
    o[4]=o45[0]; o[5]=o45[1]; o[6]=o67[0]; o[7]=o67[1];

    // merge the 4 key-stream partials per row (lanes r, r+16, r+32, r+48)
    float m = -mneg;
    #pragma unroll
    for (int mask = 16; mask <= 32; mask <<= 1){
        const float m2 = __shfl_xor(m, mask);
        const float l2 = __shfl_xor(l, mask);
        float o2[DD];
        #pragma unroll
        for (int i=0;i<DD;++i) o2[i] = __shfl_xor(o[i], mask);
        const float M  = fmaxf(m, m2);
        const float c1 = EXP2(m - M);
        const float c2 = EXP2(m2 - M);
        l = l*c1 + l2*c2;
        #pragma unroll
        for (int i=0;i<DD;++i) o[i] = o[i]*c1 + o2[i]*c2;
        m = M;
    }

    if (s == 0){
        const float inv = 1.f / l;
        const float* gp = g + base + (size_t)qrow*FF;
        float* ap = att + base + (size_t)qrow*FF;
        #pragma unroll
        for (int i=0;i<DD;++i){
            const float gate = 1.f/(1.f + __expf(-gp[i]));
            ap[i] = o[i]*inv*gate;
        }
    }
}

// ---------------- Kernel 4: output projection (tiled GEMM + GELU + LN) ----
// R13: 16-row tiles -> grid 512 blocks (was 128: HALF the CUs idle).
__global__ __launch_bounds__(256) void out_kernel(
    const float* __restrict__ att, const float* __restrict__ Wo, const float* __restrict__ bo,
    const float* __restrict__ gu, const float* __restrict__ betau,
    float* __restrict__ out0)
{
    const int rt  = blockIdx.x;          // 512 row tiles of 16
    const int tid = threadIdx.x;
    const int tx  = tid & 15;
    const int ty  = tid >> 4;
    const int r0  = rt * TN;

    __shared__ float Xs[TN][BK+2];
    __shared__ float Ws[BK][FF];
    __shared__ float boS[FF], guS[FF], beS[FF];
    if (tid < FF){ boS[tid] = bo[tid]; guS[tid] = gu[tid]; beS[tid] = betau[tid]; }

    float acc[6];
    #pragma unroll
    for (int c=0;c<6;++c) acc[c] = 0.f;

    for (int c = 0; c < 3; ++c){
        __syncthreads();
        {
            const float4* src = (const float4*)(Wo + (size_t)c*BK*FF);
            float4* dst = (float4*)&Ws[0][0];
            dst[tid      ] = src[tid      ];
            dst[tid + 256] = src[tid + 256];
            dst[tid + 512] = src[tid + 512];
        }
        {
            const float* rp = att + (size_t)(r0 + ty)*FF + c*BK;
            *(float2*)&Xs[ty][tx*2] = *(const float2*)(rp + tx*2);
        }
        __syncthreads();
        #pragma unroll 8
        for (int kk = 0; kk < BK; ++kk){
            float2 w01 = *(const float2*)&Ws[kk][6*tx    ];
            float2 w23 = *(const float2*)&Ws[kk][6*tx + 2];
            float2 w45 = *(const float2*)&Ws[kk][6*tx + 4];
            const float xv = Xs[ty][kk];
            acc[0] += xv*w01.x;  acc[1] += xv*w01.y;
            acc[2] += xv*w23.x;  acc[3] += xv*w23.y;
            acc[4] += xv*w45.x;  acc[5] += xv*w45.y;
        }
    }

    float h[6]; float psum = 0.f;
    #pragma unroll
    for (int jj=0; jj<6; ++jj){
        h[jj] = gelu_erf(acc[jj] + boS[6*tx + jj]);
        psum += h[jj];
    }
    #pragma unroll
    for (int m=1; m<16; m<<=1) psum += __shfl_xor(psum, m, 16);
    const float mu = psum * (1.f/FF);
    float vsum = 0.f;
    #pragma unroll
    for (int jj=0; jj<6; ++jj){ float d = h[jj]-mu; vsum += d*d; }
    #pragma unroll
    for (int m=1; m<16; m<<=1) vsum += __shfl_xor(vsum, m, 16);
    const float rstd = rsqrtf(vsum*(1.f/FF) + 1e-3f);
    float* __restrict__ orow = out0 + (size_t)(r0 + ty)*FF + 6*tx;
    #pragma unroll
    for (int jj=0; jj<6; ++jj)
        orow[jj] = (h[jj]-mu)*rstd*guS[6*tx+jj] + beS[6*tx+jj];
}

extern "C" void kernel_launch(void* const* d_in, const int* in_sizes, int n_in,
                              void* d_out, int out_size, void* d_ws, size_t ws_size,
                              hipStream_t stream) {
    // ---- adaptive input mapping by element count (dict-order tiebreak) ----
    int i_nodes=-1, i_ef=-1, i_edges=-1, i_ed=-1, i_ew=-1, i_Wm=-1, i_Wo=-1;
    int i_W4[4]; int nW4=0;
    int i_v96[10]; int nv96=0;
    for (int i = 0; i < n_in; ++i){
        const int s = in_sizes[i];
        if      (s == 786432)  i_nodes = i;
        else if (s == 4194304) i_ef = i;
        else if (s == 262144)  { if (i_edges < 0) i_edges = i; else i_ed = i; }
        else if (s == 131072)  i_ew = i;
        else if (s == 21504)   i_Wm = i;
        else if (s == 18432)   { if (nW4 < 4) i_W4[nW4++] = i; }
        else if (s == 9216)    i_Wo = i;
        else if (s == 96)      { if (nv96 < 10) i_v96[nv96++] = i; }
    }
    const float* nodes = (const float*)d_in[i_nodes];
    const float* ef    = (const float*)d_in[i_ef];
    const int*   edges = (const int*)d_in[i_edges];
    const float* ew    = (const float*)d_in[i_ew];
    const float* ed    = (const float*)d_in[i_ed];
    const float* Wm = (const float*)d_in[i_Wm];
    const float* Wq = (const float*)d_in[i_W4[0]];
    const float* Wk = (const float*)d_in[i_W4[1]];
    const float* Wv = (const float*)d_in[i_W4[2]];
    const float* Wg = (const float*)d_in[i_W4[3]];
    const float* Wo = (const float*)d_in[i_Wo];
    const float* bm    = (const float*)d_in[i_v96[0]];
    const float* gm    = (const float*)d_in[i_v96[1]];
    const float* betam = (const float*)d_in[i_v96[2]];
    const float* bq    = (const float*)d_in[i_v96[3]];
    const float* bk    = (const float*)d_in[i_v96[4]];
    const float* bv    = (const float*)d_in[i_v96[5]];
    const float* bg    = (const float*)d_in[i_v96[6]];
    const float* bo    = (const float*)d_in[i_v96[7]];
    const float* gu    = (const float*)d_in[i_v96[8]];
    const float* betau = (const float*)d_in[i_v96[9]];

    // ---- output layout: fp32, reference return order ----
    float* outp = (float*)d_out;
    const size_t ROWS  = (size_t)BB*NN*FF;     // 786432
    const size_t WMSZ  = (size_t)BB*EE*FF;     // 12582912
    const size_t NE2   = (size_t)BB*EE*2;      // 262144
    const size_t NW    = (size_t)BB*EE;        // 131072
    float* out_un    = outp;
    float* out_wm    = outp + ROWS;
    float* out_edges = outp + ROWS + WMSZ;
    float* out_ew    = outp + ROWS + WMSZ + NE2;
    float* out_ed    = outp + ROWS + WMSZ + NE2 + NW;

    // ---- workspace layout ----
    float* ws  = (float*)d_ws;
    float* agg = ws;
    float* qo  = ws + 1*ROWS;
    _Float16* ko_h = (_Float16*)(ws + 2*ROWS);   // K stored f16 (fdot2 path)
    float* vo  = ws + 3*ROWS;
    float* go  = ws + 4*ROWS;       // att aliases go (safe: same-thread RMW)
    float* att = go;
    // P1/P2 alias qo/ko regions: dead before qkvg_kernel writes them
    float* P1  = qo;
    float* P2  = ws + 2*ROWS;
    int* ints      = (int*)(ws + 5*ROWS);
    int* cnt       = ints;                    // B*N
    int* rowstart  = ints + BB*NN;            // B*N
    int* cursor    = ints + 2*BB*NN;          // B*N
    int* elist     = ints + 3*BB*NN;          // B*E

    hipMemsetAsync(cnt, 0, BB*NN*sizeof(int), stream);

    // CSR build (hist fused with passthrough copies — R10)
    const int npass = (int)(NE2 + NW + NE2);
    hist_kernel<<<(npass+255)/256, 256, 0, stream>>>(edges, cnt, ew, ed,
                                               out_edges, out_ew, out_ed);
    scan_kernel<<<BB, NN, 0, stream>>>(cnt, rowstart, cursor);
    scatter_kernel<<<(BB*EE+255)/256, 256, 0, stream>>>(edges, cursor, elist);

    // node projections (P1 = nodes@Wm1, P2 = nodes@Wm2) — 16-row tiles
    dim3 npgrid((BB*NN)/TN, 2);
    node_proj_kernel<<<npgrid, 256, 0, stream>>>(nodes, Wm, P1, P2);

    // edge messages: K=32 GEMM + gather-add epilogue (writes wm only)
    edge_msg2_kernel<<<(BB*EE)/TE, 256, 0, stream>>>(P1, P2, ef, edges, ew,
                                               Wm, bm, gm, betam, out_wm);
    // CSR gather -> agg
    gather_kernel<<<BB*NN, 96, 0, stream>>>(out_wm, ed, elist, rowstart, cnt, agg);

    // QKVG projections — 16-row tiles
    dim3 qgrid((BB*NN)/TN, 4);
    qkvg_kernel<<<qgrid, 256, 0, stream>>>(nodes, agg, Wq, bq, Wk, bk, Wv, bv,
                                           Wg, bg, qo, ko_h, vo, go);
    attn_kernel<<<BB*NH*16, 256, 0, stream>>>(qo, ko_h, vo, go, att);
    // output projection — 16-row tiles
    out_kernel<<<(BB*NN)/TN, 256, 0, stream>>>(att, Wo, bo, gu, betau, out_un);
}

// Round 14
// 285.447 us; speedup vs baseline: 1.0768x; 1.0768x over previous
//
#include <hip/hip_runtime.h>
#include <hip/hip_bf16.h>

#define BB 8
#define NN 1024
#define EE 16384
#define FF 96
#define FE 32
#define NH 12
#define DD 8
#define KM 224   // 2F + Fe
#define KX 192   // 2F
#define TE 64    // rows per GEMM tile (64-row: R13's 16-row retile REGRESSED
                 // +12 µs — weight restaging x4, ILP /4. Keep 64.)
#define TO 32    // rows per out_kernel tile (128 blocks was half-idle; 32-row
                 // tile -> 256 blocks = 1/CU, keeps 2 rows/thread ILP)
#define BK 32    // K chunk

#if __has_builtin(__builtin_amdgcn_exp2f)
#define EXP2(x) __builtin_amdgcn_exp2f(x)
#else
#define EXP2(x) exp2f(x)
#endif

typedef _Float16 h2 __attribute__((ext_vector_type(2)));
typedef float    f2 __attribute__((ext_vector_type(2)));

// fdot2: c + a.x*b.x + a.y*b.y with f32 accumulate (v_dot2_f32_f16).
__device__ __forceinline__ float fdot2(h2 a, h2 b, float c){
#if __has_builtin(__builtin_amdgcn_fdot2)
    return __builtin_amdgcn_fdot2(a, b, c, false);
#else
    return c + (float)a[0]*(float)b[0] + (float)a[1]*(float)b[1];
#endif
}

// Packed fp32 FMA: acc = a*b + acc on both halves (v_pk_fma_f32, VOP3P).
// R11 lesson: WIN in attn (exp2-chain loop; VGPR 56->32, occ 32->47%,
// -6.3 µs). REGRESSION in GEMM kernels (+19 µs): the opaque asm blocks
// ds_read scheduling and adds a v_mov broadcast. Use in attn ONLY.
__device__ __forceinline__ void pk_fma(f2& acc, f2 a, f2 b){
    asm("v_pk_fma_f32 %0, %1, %2, %0" : "+v"(acc) : "v"(a), "v"(b));
}

__device__ __forceinline__ float gelu_erf(float x){
    return 0.5f * x * (1.0f + erff(x * 0.70710678118654752f));
}

__device__ __forceinline__ int load_idx(const int* __restrict__ p, int i){
    int v = p[i];
    if (!((unsigned)v < 1024u)) v = (int)__int_as_float(v);
    return min(max(v, 0), NN-1);
}

// ---------------- CSR build: histogram + FUSED passthrough outputs ----------
// NOTE (R7): do NOT replace the CSR subsystem with fused fp32 atomicAdd into
// agg — device-scope atomics bypass the per-XCD L2 (not cross-coherent):
// measured 344 MB WRITE_SIZE and a 269 µs edge kernel. CSR+gather is ~10x
// cheaper.
__global__ __launch_bounds__(256) void hist_kernel(
    const int* __restrict__ edges, int* __restrict__ cnt,
    const float* __restrict__ ew, const float* __restrict__ ed,
    float* __restrict__ o_edges, float* __restrict__ o_ew, float* __restrict__ o_ed)
{
    const int i = blockIdx.x*blockDim.x + threadIdx.x;
    if (i < BB*EE){
        const int b = i >> 14;
        const int dst = load_idx(edges, 2*i+1);
        atomicAdd(&cnt[b*NN + dst], 1);
    }
    const int NE2 = BB*EE*2;
    const int NW  = BB*EE;
    if (i < NE2)                 o_edges[i] = (float)load_idx(edges, i);
    else if (i < NE2+NW)         o_ew[i-NE2] = ew[i-NE2];
    else if (i < NE2+NW+NE2)     o_ed[i-NE2-NW] = ed[i-NE2-NW];
}

// ---------------- CSR build: per-batch exclusive scan (N=1024) ----------------
__global__ __launch_bounds__(1024) void scan_kernel(
    const int* __restrict__ cnt, int* __restrict__ rowstart, int* __restrict__ cursor)
{
    const int b = blockIdx.x;
    const int t = threadIdx.x;
    __shared__ int s[NN];
    const int v = cnt[b*NN + t];
    s[t] = v;
    __syncthreads();
    for (int off = 1; off < NN; off <<= 1){
        int u = (t >= off) ? s[t-off] : 0;
        __syncthreads();
        s[t] += u;
        __syncthreads();
    }
    const int ex = s[t] - v + b*EE;     // exclusive, offset by batch base
    rowstart[b*NN + t] = ex;
    cursor[b*NN + t]   = ex;
}

// ---------------- CSR build: scatter edge ids ----------------
__global__ __launch_bounds__(256) void scatter_kernel(
    const int* __restrict__ edges, int* __restrict__ cursor, int* __restrict__ elist)
{
    const int i = blockIdx.x*blockDim.x + threadIdx.x;   // global edge id
    if (i < BB*EE){
        const int b = i >> 14;
        const int dst = load_idx(edges, 2*i+1);
        const int pos = atomicAdd(&cursor[b*NN + dst], 1);
        elist[pos] = i;
    }
}

// ---------------- Kernel 0: node projections P1 = nodes@Wm1, P2 = nodes@Wm2 ----
// msg = concat(src,dst,ef)@Wm decomposes as src@Wm1 + dst@Wm2 + ef@Wm3.
// Node terms shared across edges -> precompute once (R2 factorization).
// 64-row tiles, scalar FMA inner loop (R11/R13 lessons).
__global__ __launch_bounds__(256) void node_proj_kernel(
    const float* __restrict__ nodes, const float* __restrict__ Wm,
    float* __restrict__ P1, float* __restrict__ P2)
{
    const int rt  = blockIdx.x;          // 128 row tiles
    const int m   = blockIdx.y;          // 0: src-proj, 1: dst-proj
    const int tid = threadIdx.x;
    const int tx  = tid & 15;
    const int ty  = tid >> 4;
    const int r0  = rt * TE;

    const float* W = Wm + (size_t)(m ? FF : 0) * FF;   // rows [0,96) or [96,192)
    float* out     = m ? P2 : P1;

    __shared__ float Xs[TE][BK+4];
    __shared__ float Ws[BK][FF];

    float acc[4][6];
    #pragma unroll
    for (int a=0;a<4;++a)
        #pragma unroll
        for (int c=0;c<6;++c) acc[a][c] = 0.f;

    const int e_st = tid >> 2;
    const int kk0  = (tid & 3) * 8;

    for (int c = 0; c < 3; ++c){
        __syncthreads();
        {
            const float4* src = (const float4*)(W + (size_t)c*BK*FF);
            float4* dst = (float4*)&Ws[0][0];
            dst[tid      ] = src[tid      ];
            dst[tid + 256] = src[tid + 256];
            dst[tid + 512] = src[tid + 512];
        }
        {
            const float* rp = nodes + (size_t)(r0 + e_st)*FF + c*BK;
            *(float4*)&Xs[e_st][kk0    ] = *(const float4*)(rp + kk0);
            *(float4*)&Xs[e_st][kk0 + 4] = *(const float4*)(rp + kk0 + 4);
        }
        __syncthreads();
        #pragma unroll 4
        for (int kk = 0; kk < BK; ++kk){
            float2 w01 = *(const float2*)&Ws[kk][6*tx    ];
            float2 w23 = *(const float2*)&Ws[kk][6*tx + 2];
            float2 w45 = *(const float2*)&Ws[kk][6*tx + 4];
            float xv[4];
            #pragma unroll
            for (int ei=0; ei<4; ++ei) xv[ei] = Xs[ty + 16*ei][kk];
            #pragma unroll
            for (int ei=0; ei<4; ++ei){
                acc[ei][0] += xv[ei]*w01.x;  acc[ei][1] += xv[ei]*w01.y;
                acc[ei][2] += xv[ei]*w23.x;  acc[ei][3] += xv[ei]*w23.y;
                acc[ei][4] += xv[ei]*w45.x;  acc[ei][5] += xv[ei]*w45.y;
            }
        }
    }

    #pragma unroll
    for (int ei = 0; ei < 4; ++ei){
        const int row = r0 + ty + 16*ei;
        float* __restrict__ orow = out + (size_t)row*FF + 6*tx;
        #pragma unroll
        for (int jj=0; jj<6; ++jj) orow[jj] = acc[ei][jj];
    }
}

// ---------------- Kernel 1: edge messages (K=32 GEMM + gather-add epilogue) ----
__global__ __launch_bounds__(256) void edge_msg2_kernel(
    const float* __restrict__ P1, const float* __restrict__ P2,
    const float* __restrict__ ef,
    const int*  __restrict__ edges, const float* __restrict__ ew,
    const float* __restrict__ Wm, const float* __restrict__ bm,
    const float* __restrict__ gm, const float* __restrict__ betam,
    float* __restrict__ wm_out)
{
    const int bid = blockIdx.x;
    const int tid = threadIdx.x;
    const int tx  = tid & 15;
    const int ty  = tid >> 4;
    const int be0 = bid * TE;
    const int b   = be0 >> 14;

    __shared__ float Xs[TE][BK+4];
    __shared__ float Ws[BK][FF];
    __shared__ int   eidx[TE*2];
    __shared__ float ewS[TE];
    __shared__ float bmS[FF], gmS[FF], betamS[FF];

    if (tid < TE*2){
        int v = edges[(size_t)be0*2 + tid];
        if (!((unsigned)v < 1024u)) v = (int)__int_as_float(v);
        eidx[tid] = min(max(v, 0), NN-1);
    }
    if (tid < TE) ewS[tid] = ew[be0 + tid];
    if (tid < FF){ bmS[tid] = bm[tid]; gmS[tid] = gm[tid]; betamS[tid] = betam[tid]; }

    float acc[4][6];
    #pragma unroll
    for (int a=0;a<4;++a)
        #pragma unroll
        for (int c=0;c<6;++c) acc[a][c] = 0.f;

    const int e_st = tid >> 2;
    const int kk0  = (tid & 3) * 8;

    // ---- single K=32 chunk: ef @ Wm[192:224] ----
    {
        const float4* src = (const float4*)(Wm + (size_t)KX*FF);
        float4* dst = (float4*)&Ws[0][0];
        dst[tid      ] = src[tid      ];
        dst[tid + 256] = src[tid + 256];
        dst[tid + 512] = src[tid + 512];
    }
    {
        const float* rp = ef + (size_t)(be0 + e_st)*FE;
        *(float4*)&Xs[e_st][kk0    ] = *(const float4*)(rp + kk0);
        *(float4*)&Xs[e_st][kk0 + 4] = *(const float4*)(rp + kk0 + 4);
    }
    __syncthreads();
    #pragma unroll 4
    for (int kk = 0; kk < BK; ++kk){
        float2 w01 = *(const float2*)&Ws[kk][6*tx    ];
        float2 w23 = *(const float2*)&Ws[kk][6*tx + 2];
        float2 w45 = *(const float2*)&Ws[kk][6*tx + 4];
        float xv[4];
        #pragma unroll
        for (int ei=0; ei<4; ++ei) xv[ei] = Xs[ty + 16*ei][kk];
        #pragma unroll
        for (int ei=0; ei<4; ++ei){
            acc[ei][0] += xv[ei]*w01.x;  acc[ei][1] += xv[ei]*w01.y;
            acc[ei][2] += xv[ei]*w23.x;  acc[ei][3] += xv[ei]*w23.y;
            acc[ei][4] += xv[ei]*w45.x;  acc[ei][5] += xv[ei]*w45.y;
        }
    }

    // ---- prefetch node-projection gathers for all 4 rows (hide L2 latency) ----
    float add[4][6];
    #pragma unroll
    for (int ei = 0; ei < 4; ++ei){
        const int el = ty + 16*ei;
        const int sn = eidx[2*el];
        const int dn = eidx[2*el+1];
        const float2* p1 = (const float2*)(P1 + (size_t)(b*NN + sn)*FF + 6*tx);
        const float2* p2 = (const float2*)(P2 + (size_t)(b*NN + dn)*FF + 6*tx);
        const float2 a0 = p1[0], a1 = p1[1], a2 = p1[2];
        const float2 b0 = p2[0], b1 = p2[1], b2 = p2[2];
        add[ei][0] = a0.x + b0.x;  add[ei][1] = a0.y + b0.y;
        add[ei][2] = a1.x + b1.x;  add[ei][3] = a1.y + b1.y;
        add[ei][4] = a2.x + b2.x;  add[ei][5] = a2.y + b2.y;
    }

    #pragma unroll
    for (int ei = 0; ei < 4; ++ei){
        const int el = ty + 16*ei;
        float h[6]; float psum = 0.f;
        #pragma unroll
        for (int jj=0; jj<6; ++jj){
            h[jj] = gelu_erf(acc[ei][jj] + add[ei][jj] + bmS[6*tx + jj]);
            psum += h[jj];
        }
        #pragma unroll
        for (int m=1; m<16; m<<=1) psum += __shfl_xor(psum, m, 16);
        const float mu = psum * (1.f/FF);
        float vsum = 0.f;
        #pragma unroll
        for (int jj=0; jj<6; ++jj){ float d = h[jj]-mu; vsum += d*d; }
        #pragma unroll
        for (int m=1; m<16; m<<=1) vsum += __shfl_xor(vsum, m, 16);
        const float rstd = rsqrtf(vsum*(1.f/FF) + 1e-3f);

        const float w = ewS[el];
        float* __restrict__ wrow = wm_out + (size_t)(be0 + el)*FF + 6*tx;
        #pragma unroll
        for (int jj=0; jj<6; ++jj)
            wrow[jj] = ((h[jj]-mu)*rstd*gmS[6*tx+jj] + betamS[6*tx+jj]) * w;
    }
}

// ---------------- Kernel 1b: CSR gather -> agg ----------------
__global__ __launch_bounds__(96) void gather_kernel(
    const float* __restrict__ wm_out, const float* __restrict__ ed,
    const int* __restrict__ elist, const int* __restrict__ rowstart,
    const int* __restrict__ cnt, float* __restrict__ agg)
{
    const int bn = blockIdx.x;       // b*N + n
    const int t  = threadIdx.x;      // 96
    const int beg = rowstart[bn];
    const int num = cnt[bn];
    float sum = 0.f;
    for (int i = 0; i < num; ++i){
        const int be = elist[beg + i];
        const float coeff = ed[2*(size_t)be + 1];
        sum += wm_out[(size_t)be*FF + t] * coeff;
    }
    agg[(size_t)bn*FF + t] = sum;
}

// ---------------- Kernel 2: QKVG projections (tiled GEMM) ----------------
// 64-row tiles (R13 retile regressed), scalar FMA loop. K (m==1) written
// f16 for attn's v_dot2_f32_f16 path (R8).
__global__ __launch_bounds__(256) void qkvg_kernel(
    const float* __restrict__ nodes, const float* __restrict__ agg,
    const float* __restrict__ Wq, const float* __restrict__ bq,
    const float* __restrict__ Wk, const float* __restrict__ bk,
    const float* __restrict__ Wv, const float* __restrict__ bv,
    const float* __restrict__ Wg, const float* __restrict__ bg,
    float* __restrict__ qo, _Float16* __restrict__ ko_h,
    float* __restrict__ vo, float* __restrict__ go)
{
    const int rt  = blockIdx.x;          // 128 row tiles
    const int m   = blockIdx.y;          // 0..3
    const int tid = threadIdx.x;
    const int tx  = tid & 15;
    const int ty  = tid >> 4;
    const int r0  = rt * TE;

    const float* W    = (m==0)?Wq:(m==1)?Wk:(m==2)?Wv:Wg;
    const float* bias = (m==0)?bq:(m==1)?bk:(m==2)?bv:bg;
    float* out        = (m==0)?qo:(m==2)?vo:go;   // m==1 -> ko_h (f16 path)

    __shared__ float Xs[TE][BK+4];
    __shared__ float Ws[BK][FF];
    __shared__ float bS[FF];
    if (tid < FF) bS[tid] = bias[tid];

    float acc[4][6];
    #pragma unroll
    for (int a=0;a<4;++a)
        #pragma unroll
        for (int c=0;c<6;++c) acc[a][c] = 0.f;

    const int e_st = tid >> 2;
    const int kk0  = (tid & 3) * 8;

    for (int c = 0; c < 6; ++c){
        __syncthreads();
        {
            const float4* src = (const float4*)(W + (size_t)c*BK*FF);
            float4* dst = (float4*)&Ws[0][0];
            dst[tid      ] = src[tid      ];
            dst[tid + 256] = src[tid + 256];
            dst[tid + 512] = src[tid + 512];
        }
        {
            const float* rp = (c < 3)
                ? nodes + (size_t)(r0 + e_st)*FF + c*BK
                : agg   + (size_t)(r0 + e_st)*FF + (c-3)*BK;
            *(float4*)&Xs[e_st][kk0    ] = *(const float4*)(rp + kk0);
            *(float4*)&Xs[e_st][kk0 + 4] = *(const float4*)(rp + kk0 + 4);
        }
        __syncthreads();
        #pragma unroll 4
        for (int kk = 0; kk < BK; ++kk){
            float2 w01 = *(const float2*)&Ws[kk][6*tx    ];
            float2 w23 = *(const float2*)&Ws[kk][6*tx + 2];
            float2 w45 = *(const float2*)&Ws[kk][6*tx + 4];
            float xv[4];
            #pragma unroll
            for (int ei=0; ei<4; ++ei) xv[ei] = Xs[ty + 16*ei][kk];
            #pragma unroll
            for (int ei=0; ei<4; ++ei){
                acc[ei][0] += xv[ei]*w01.x;  acc[ei][1] += xv[ei]*w01.y;
                acc[ei][2] += xv[ei]*w23.x;  acc[ei][3] += xv[ei]*w23.y;
                acc[ei][4] += xv[ei]*w45.x;  acc[ei][5] += xv[ei]*w45.y;
            }
        }
    }

    if (m == 1){
        #pragma unroll
        for (int ei = 0; ei < 4; ++ei){
            const int row = r0 + ty + 16*ei;
            _Float16* __restrict__ orow = ko_h + (size_t)row*FF + 6*tx;
            #pragma unroll
            for (int jj=0; jj<6; ++jj) orow[jj] = (_Float16)(acc[ei][jj] + bS[6*tx + jj]);
        }
    } else {
        #pragma unroll
        for (int ei = 0; ei < 4; ++ei){
            const int row = r0 + ty + 16*ei;
            float* __restrict__ orow = out + (size_t)row*FF + 6*tx;
            #pragma unroll
            for (int jj=0; jj<6; ++jj) orow[jj] = acc[ei][jj] + bS[6*tx + jj];
        }
    }
}

// ---------------- Kernel 3: gated attention (LDS-staged flash) ----------
// block = 256 thr = 4 waves per (b, h, 64-row q-tile). R2 lane decomp
// (1 q-row/lane, 16 rows x 4 key-streams) + exp2 rebase + fdot2 QK (R9)
// + -m-seeded dot chain + max3 group max (R10) + pk_fma PV (R11: 67.3 µs,
// VGPR 32, occ 47%) + single 8 KB LDS buffer with register prefetch.
// att MAY alias g: final phase reads g then writes att from same thread.
__global__ __launch_bounds__(256) void attn_kernel(
    const float* __restrict__ q, const _Float16* __restrict__ kh,
    const float* __restrict__ v, const float* g,
    float* att)
{
    const int blk = blockIdx.x;
    const int qt = blk & 15;              // N/64 = 16 tiles
    const int h  = (blk >> 4) % NH;
    const int b  = blk / (16*NH);
    const int tid  = threadIdx.x;
    const int lane = tid & 63;
    const int w    = tid >> 6;            // wave id 0..3
    const int r    = lane & 15;           // row within wave
    const int s    = lane >> 4;           // key stream 0..3
    const int qrow = qt*64 + w*16 + r;
    const size_t base = (size_t)(b*NN)*FF + h*DD;

    __shared__ _Float16 Ks[128][8];       // 16 B rows (2 KB): 1 b128 = whole K row
    __shared__ float    Vs[128][12];      // 48 B rows (6 KB), conflict-free

    // Q -> f16 pairs, pre-scaled by log2(e)/sqrt(8) for the exp2 softmax
    h2 qh[4];
    {
        const float* qp = q + base + (size_t)qrow*FF;
        #pragma unroll
        for (int i=0;i<4;++i){
            qh[i][0] = (_Float16)(qp[2*i  ] * 0.51010300101462254f);
            qh[i][1] = (_Float16)(qp[2*i+1] * 0.51010300101462254f);
        }
    }

    // mneg = -m (running max, log2 domain), m starts at 0 (R10).
    float mneg = 0.f, l = 0.f;
    f2 o01 = (f2){0.f,0.f}, o23 = (f2){0.f,0.f};
    f2 o45 = (f2){0.f,0.f}, o67 = (f2){0.f,0.f};

    const int skey  = tid >> 1;           // staging: 2 threads per key
    const int half8 = (tid & 1) * 4;      // K: halfs 0-3 / 4-7 ; V: floats 0-3 / 4-7

    // prologue: fetch chunk 0 into regs (K row = 8 B per thread, V = 16 B)
    float2 kreg = *(const float2*)(kh + base + (size_t)skey*FF + half8);
    float4 vreg = *(const float4*)(v  + base + (size_t)skey*FF + half8);

    for (int t = 0; t < 8; ++t){
        // write staged regs (waits vmcnt for kreg/vreg only)
        *(float2*)&Ks[skey][half8] = kreg;
        *(float4*)&Vs[skey][half8] = vreg;
        __syncthreads();
        // issue next chunk's loads NOW; latency hides under compute below
        if (t < 7){
            kreg = *(const float2*)(kh + base + (size_t)((t+1)*128 + skey)*FF + half8);
            vreg = *(const float4*)(v  + base + (size_t)((t+1)*128 + skey)*FF + half8);
        }
        #pragma unroll
        for (int gidx = 0; gidx < 4; ++gidx){
            // pass 1: 8 score dots, chain seeded with -m (already subtracted)
            float sc[8];
            #pragma unroll
            for (int jj = 0; jj < 8; ++jj){
                const int key = 32*gidx + 4*jj + s;
                float4 kraw = *(const float4*)&Ks[key][0];   // 8 halfs
                const h2* kp = (const h2*)&kraw;
                sc[jj] = fdot2(qh[3], kp[3],
                         fdot2(qh[2], kp[2],
                         fdot2(qh[1], kp[1],
                         fdot2(qh[0], kp[0], mneg))));
            }
            // group max via max3-shaped nests (v_max3_f32) + rare rescale
            const float t0 = fmaxf(fmaxf(sc[0], sc[1]), sc[2]);
            const float t1 = fmaxf(fmaxf(sc[3], sc[4]), sc[5]);
            const float t2 = fmaxf(fmaxf(sc[6], sc[7]), t0);
            const float gmax = fmaxf(t1, t2);     // = max(sc[0..7]) (rel. to m)
            if (gmax > 11.5f){
                const float c = EXP2(-gmax);
                l *= c;
                o01[0]*=c; o01[1]*=c; o23[0]*=c; o23[1]*=c;
                o45[0]*=c; o45[1]*=c; o67[0]*=c; o67[1]*=c;
                mneg -= gmax;
                #pragma unroll
                for (int jj=0;jj<8;++jj) sc[jj] -= gmax;
            }
            // pass 2: exp2 + packed PV accumulate (v_pk_fma_f32)
            #pragma unroll
            for (int jj = 0; jj < 8; ++jj){
                const int key = 32*gidx + 4*jj + s;
                float4 v0 = *(const float4*)&Vs[key][0];
                float4 v1 = *(const float4*)&Vs[key][4];
                const f2* va = (const f2*)&v0;
                const f2* vb = (const f2*)&v1;
                const float p = EXP2(sc[jj]);
                l += p;
                f2 p2 = (f2){p, p};
                pk_fma(o01, p2, va[0]);
                pk_fma(o23, p2, va[1]);
                pk_fma(o45, p2, vb[0]);
                pk_fma(o67, p2, vb[1]);
            }
        }
        if (t < 7) __syncthreads();       // all reads done before overwrite
    }

    // unpack pairs for the cross-stream merge
    float o[DD];
    o[0]=o01[0]; o[1]=o01[1]; o[2]=o23[0]; o[3]=o23[1];
    o[4]=o45[0]; o[5]=o45[1]; o[6]=o67[0]; o[7]=o67[1];

    // merge the 4 key-stream partials per row (lanes r, r+16, r+32, r+48)
    float m = -mneg;
    #pragma unroll
    for (int mask = 16; mask <= 32; mask <<= 1){
        const float m2 = __shfl_xor(m, mask);
        const float l2 = __shfl_xor(l, mask);
        float o2[DD];
        #pragma unroll
        for (int i=0;i<DD;++i) o2[i] = __shfl_xor(o[i], mask);
        const float M  = fmaxf(m, m2);
        const float c1 = EXP2(m - M);
        const float c2 = EXP2(m2 - M);
        l = l*c1 + l2*c2;
        #pragma unroll
        for (int i=0;i<DD;++i) o[i] = o[i]*c1 + o2[i]*c2;
        m = M;
    }

    if (s == 0){
        const float inv = 1.f / l;
        const float* gp = g + base + (size_t)qrow*FF;
        float* ap = att + base + (size_t)qrow*FF;
        #pragma unroll
        for (int i=0;i<DD;++i){
            const float gate = 1.f/(1.f + __expf(-gp[i]));
            ap[i] = o[i]*inv*gate;
        }
    }
}

// ---------------- Kernel 4: output projection (tiled GEMM + GELU + LN) ----
// TO=32-row tiles -> 256 blocks (1/CU; was 128 = half the chip idle).
// 2 rows/thread keeps 12-output ILP; weight restaging only x2 (L2-hit).
__global__ __launch_bounds__(256) void out_kernel(
    const float* __restrict__ att, const float* __restrict__ Wo, const float* __restrict__ bo,
    const float* __restrict__ gu, const float* __restrict__ betau,
    float* __restrict__ out0)
{
    const int rt  = blockIdx.x;          // 256 row tiles of 32
    const int tid = threadIdx.x;
    const int tx  = tid & 15;
    const int ty  = tid >> 4;
    const int r0  = rt * TO;

    __shared__ float Xs[TO][BK+4];
    __shared__ float Ws[BK][FF];
    __shared__ float boS[FF], guS[FF], beS[FF];
    if (tid < FF){ boS[tid] = bo[tid]; guS[tid] = gu[tid]; beS[tid] = betau[tid]; }

    float acc[2][6];
    #pragma unroll
    for (int a=0;a<2;++a)
        #pragma unroll
        for (int c=0;c<6;++c) acc[a][c] = 0.f;

    const int e_st = tid >> 3;           // 0..31: row within tile
    const int kk0  = (tid & 7) * 4;      // 0..28: 4 floats per thread

    for (int c = 0; c < 3; ++c){
        __syncthreads();
        {
            const float4* src = (const float4*)(Wo + (size_t)c*BK*FF);
            float4* dst = (float4*)&Ws[0][0];
            dst[tid      ] = src[tid      ];
            dst[tid + 256] = src[tid + 256];
            dst[tid + 512] = src[tid + 512];
        }
        {
            const float* rp = att + (size_t)(r0 + e_st)*FF + c*BK;
            *(float4*)&Xs[e_st][kk0] = *(const float4*)(rp + kk0);
        }
        __syncthreads();
        #pragma unroll 4
        for (int kk = 0; kk < BK; ++kk){
            float2 w01 = *(const float2*)&Ws[kk][6*tx    ];
            float2 w23 = *(const float2*)&Ws[kk][6*tx + 2];
            float2 w45 = *(const float2*)&Ws[kk][6*tx + 4];
            float xv[2];
            xv[0] = Xs[ty     ][kk];
            xv[1] = Xs[ty + 16][kk];
            #pragma unroll
            for (int ei=0; ei<2; ++ei){
                acc[ei][0] += xv[ei]*w01.x;  acc[ei][1] += xv[ei]*w01.y;
                acc[ei][2] += xv[ei]*w23.x;  acc[ei][3] += xv[ei]*w23.y;
                acc[ei][4] += xv[ei]*w45.x;  acc[ei][5] += xv[ei]*w45.y;
            }
        }
    }

    #pragma unroll
    for (int ei = 0; ei < 2; ++ei){
        const int row = r0 + ty + 16*ei;
        float h[6]; float psum = 0.f;
        #pragma unroll
        for (int jj=0; jj<6; ++jj){
            h[jj] = gelu_erf(acc[ei][jj] + boS[6*tx + jj]);
            psum += h[jj];
        }
        #pragma unroll
        for (int m=1; m<16; m<<=1) psum += __shfl_xor(psum, m, 16);
        const float mu = psum * (1.f/FF);
        float vsum = 0.f;
        #pragma unroll
        for (int jj=0; jj<6; ++jj){ float d = h[jj]-mu; vsum += d*d; }
        #pragma unroll
        for (int m=1; m<16; m<<=1) vsum += __shfl_xor(vsum, m, 16);
        const float rstd = rsqrtf(vsum*(1.f/FF) + 1e-3f);
        float* __restrict__ orow = out0 + (size_t)row*FF + 6*tx;
        #pragma unroll
        for (int jj=0; jj<6; ++jj)
            orow[jj] = (h[jj]-mu)*rstd*guS[6*tx+jj] + beS[6*tx+jj];
    }
}

extern "C" void kernel_launch(void* const* d_in, const int* in_sizes, int n_in,
                              void* d_out, int out_size, void* d_ws, size_t ws_size,
                              hipStream_t stream) {
    // ---- adaptive input mapping by element count (dict-order tiebreak) ----
    int i_nodes=-1, i_ef=-1, i_edges=-1, i_ed=-1, i_ew=-1, i_Wm=-1, i_Wo=-1;
    int i_W4[4]; int nW4=0;
    int i_v96[10]; int nv96=0;
    for (int i = 0; i < n_in; ++i){
        const int s = in_sizes[i];
        if      (s == 786432)  i_nodes = i;
        else if (s == 4194304) i_ef = i;
        else if (s == 262144)  { if (i_edges < 0) i_edges = i; else i_ed = i; }
        else if (s == 131072)  i_ew = i;
        else if (s == 21504)   i_Wm = i;
        else if (s == 18432)   { if (nW4 < 4) i_W4[nW4++] = i; }
        else if (s == 9216)    i_Wo = i;
        else if (s == 96)      { if (nv96 < 10) i_v96[nv96++] = i; }
    }
    const float* nodes = (const float*)d_in[i_nodes];
    const float* ef    = (const float*)d_in[i_ef];
    const int*   edges = (const int*)d_in[i_edges];
    const float* ew    = (const float*)d_in[i_ew];
    const float* ed    = (const float*)d_in[i_ed];
    const float* Wm = (const float*)d_in[i_Wm];
    const float* Wq = (const float*)d_in[i_W4[0]];
    const float* Wk = (const float*)d_in[i_W4[1]];
    const float* Wv = (const float*)d_in[i_W4[2]];
    const float* Wg = (const float*)d_in[i_W4[3]];
    const float* Wo = (const float*)d_in[i_Wo];
    const float* bm    = (const float*)d_in[i_v96[0]];
    const float* gm    = (const float*)d_in[i_v96[1]];
    const float* betam = (const float*)d_in[i_v96[2]];
    const float* bq    = (const float*)d_in[i_v96[3]];
    const float* bk    = (const float*)d_in[i_v96[4]];
    const float* bv    = (const float*)d_in[i_v96[5]];
    const float* bg    = (const float*)d_in[i_v96[6]];
    const float* bo    = (const float*)d_in[i_v96[7]];
    const float* gu    = (const float*)d_in[i_v96[8]];
    const float* betau = (const float*)d_in[i_v96[9]];

    // ---- output layout: fp32, reference return order ----
    float* outp = (float*)d_out;
    const size_t ROWS  = (size_t)BB*NN*FF;     // 786432
    const size_t WMSZ  = (size_t)BB*EE*FF;     // 12582912
    const size_t NE2   = (size_t)BB*EE*2;      // 262144
    const size_t NW    = (size_t)BB*EE;        // 131072
    float* out_un    = outp;
    float* out_wm    = outp + ROWS;
    float* out_edges = outp + ROWS + WMSZ;
    float* out_ew    = outp + ROWS + WMSZ + NE2;
    float* out_ed    = outp + ROWS + WMSZ + NE2 + NW;

    // ---- workspace layout ----
    float* ws  = (float*)d_ws;
    float* agg = ws;
    float* qo  = ws + 1*ROWS;
    _Float16* ko_h = (_Float16*)(ws + 2*ROWS);   // K stored f16 (fdot2 path)
    float* vo  = ws + 3*ROWS;
    float* go  = ws + 4*ROWS;       // att aliases go (safe: same-thread RMW)
    float* att = go;
    // P1/P2 alias qo/ko regions: dead before qkvg_kernel writes them
    float* P1  = qo;
    float* P2  = ws + 2*ROWS;
    int* ints      = (int*)(ws + 5*ROWS);
    int* cnt       = ints;                    // B*N
    int* rowstart  = ints + BB*NN;            // B*N
    int* cursor    = ints + 2*BB*NN;          // B*N
    int* elist     = ints + 3*BB*NN;          // B*E

    hipMemsetAsync(cnt, 0, BB*NN*sizeof(int), stream);

    // CSR build (hist fused with passthrough copies — R10)
    const int npass = (int)(NE2 + NW + NE2);
    hist_kernel<<<(npass+255)/256, 256, 0, stream>>>(edges, cnt, ew, ed,
                                               out_edges, out_ew, out_ed);
    scan_kernel<<<BB, NN, 0, stream>>>(cnt, rowstart, cursor);
    scatter_kernel<<<(BB*EE+255)/256, 256, 0, stream>>>(edges, cursor, elist);

    // node projections (P1 = nodes@Wm1, P2 = nodes@Wm2) — 64-row tiles
    dim3 npgrid((BB*NN)/TE, 2);
    node_proj_kernel<<<npgrid, 256, 0, stream>>>(nodes, Wm, P1, P2);

    // edge messages: K=32 GEMM + gather-add epilogue (writes wm only)
    edge_msg2_kernel<<<(BB*EE)/TE, 256, 0, stream>>>(P1, P2, ef, edges, ew,
                                               Wm, bm, gm, betam, out_wm);
    // CSR gather -> agg
    gather_kernel<<<BB*NN, 96, 0, stream>>>(out_wm, ed, elist, rowstart, cnt, agg);

    // QKVG projections — 64-row tiles
    dim3 qgrid((BB*NN)/TE, 4);
    qkvg_kernel<<<qgrid, 256, 0, stream>>>(nodes, agg, Wq, bq, Wk, bk, Wv, bv,
                                           Wg, bg, qo, ko_h, vo, go);
    attn_kernel<<<BB*NH*16, 256, 0, stream>>>(qo, ko_h, vo, go, att);
    // output projection — 32-row tiles (256 blocks)
    out_kernel<<<(BB*NN)/TO, 256, 0, stream>>>(att, Wo, bo, gu, betau, out_un);
}

// Round 15
// 271.466 us; speedup vs baseline: 1.1323x; 1.0515x over previous
//
#include <hip/hip_runtime.h>
#include <hip/hip_bf16.h>

#define BB 8
#define NN 1024
#define EE 16384
#define FF 96
#define FE 32
#define NH 12
#define DD 8
#define KM 224   // 2F + Fe
#define KX 192   // 2F
#define TE 64    // rows per GEMM tile (R13's 16-row retile regressed; keep 64)
#define TO 32    // rows per out_kernel tile (256 blocks = 1/CU; R14 win)
#define BK 32    // K chunk
#define SLOTS 64 // bucket capacity per node (Poisson(16) degree; P(>=64)~1e-19)

#if __has_builtin(__builtin_amdgcn_exp2f)
#define EXP2(x) __builtin_amdgcn_exp2f(x)
#else
#define EXP2(x) exp2f(x)
#endif

typedef _Float16 h2 __attribute__((ext_vector_type(2)));
typedef float    f2 __attribute__((ext_vector_type(2)));

// fdot2: c + a.x*b.x + a.y*b.y with f32 accumulate (v_dot2_f32_f16).
__device__ __forceinline__ float fdot2(h2 a, h2 b, float c){
#if __has_builtin(__builtin_amdgcn_fdot2)
    return __builtin_amdgcn_fdot2(a, b, c, false);
#else
    return c + (float)a[0]*(float)b[0] + (float)a[1]*(float)b[1];
#endif
}

// Packed fp32 FMA: acc = a*b + acc on both halves (v_pk_fma_f32, VOP3P).
// R11 lesson: WIN in attn (exp2-chain loop; VGPR 56->32, occ 32->47%,
// -6.3 µs). REGRESSION in GEMM kernels (+19 µs): the opaque asm blocks
// ds_read scheduling and adds a v_mov broadcast. Use in attn ONLY.
__device__ __forceinline__ void pk_fma(f2& acc, f2 a, f2 b){
    asm("v_pk_fma_f32 %0, %1, %2, %0" : "+v"(acc) : "v"(a), "v"(b));
}

__device__ __forceinline__ float gelu_erf(float x){
    return 0.5f * x * (1.0f + erff(x * 0.70710678118654752f));
}

__device__ __forceinline__ int load_idx(const int* __restrict__ p, int i){
    int v = p[i];
    if (!((unsigned)v < 1024u)) v = (int)__int_as_float(v);
    return min(max(v, 0), NN-1);
}

// ---------------- CSR replaced by bucket append (R15) ----------------
// hist+scan+scatter (3 launches; scan ran on 8 BLOCKS = 3% of the chip
// through 10 barrier rounds) replaced by ONE atomic bucket-append kernel:
// pos = atomicAdd(cnt[bn]); elist[bn*64+pos] = edge. rowstart == bn*64.
// NOTE (R7): do NOT fuse fp32 atomicAdd aggregation into the edge GEMM —
// device-scope fp32 atomics bypass per-XCD L2: 344 MB WRITE_SIZE, 269 µs.
// INT bucket atomics here are 1 per edge (vs 96 fp32 per edge) — cheap.
// Passthrough copies (edges/ew/ed -> fp32 outputs) fused here too.
__global__ __launch_bounds__(256) void scatter_kernel(
    const int* __restrict__ edges, int* __restrict__ cnt, int* __restrict__ elist,
    const float* __restrict__ ew, const float* __restrict__ ed,
    float* __restrict__ o_edges, float* __restrict__ o_ew, float* __restrict__ o_ed)
{
    const int i = blockIdx.x*blockDim.x + threadIdx.x;
    if (i < BB*EE){
        const int b = i >> 14;
        const int dst = load_idx(edges, 2*i+1);
        const int bn = b*NN + dst;
        const int pos = atomicAdd(&cnt[bn], 1);
        if (pos < SLOTS) elist[bn*SLOTS + pos] = i;
    }
    const int NE2 = BB*EE*2;
    const int NW  = BB*EE;
    if (i < NE2)                 o_edges[i] = (float)load_idx(edges, i);
    else if (i < NE2+NW)         o_ew[i-NE2] = ew[i-NE2];
    else if (i < NE2+NW+NE2)     o_ed[i-NE2-NW] = ed[i-NE2-NW];
}

// ---------------- Kernel 0: node projections P1 = nodes@Wm1, P2 = nodes@Wm2 ----
// msg = concat(src,dst,ef)@Wm decomposes as src@Wm1 + dst@Wm2 + ef@Wm3.
// Node terms shared across edges -> precompute once (R2 factorization).
// 64-row tiles, scalar FMA inner loop (R11/R13 lessons).
__global__ __launch_bounds__(256) void node_proj_kernel(
    const float* __restrict__ nodes, const float* __restrict__ Wm,
    float* __restrict__ P1, float* __restrict__ P2)
{
    const int rt  = blockIdx.x;          // 128 row tiles
    const int m   = blockIdx.y;          // 0: src-proj, 1: dst-proj
    const int tid = threadIdx.x;
    const int tx  = tid & 15;
    const int ty  = tid >> 4;
    const int r0  = rt * TE;

    const float* W = Wm + (size_t)(m ? FF : 0) * FF;   // rows [0,96) or [96,192)
    float* out     = m ? P2 : P1;

    __shared__ float Xs[TE][BK+4];
    __shared__ float Ws[BK][FF];

    float acc[4][6];
    #pragma unroll
    for (int a=0;a<4;++a)
        #pragma unroll
        for (int c=0;c<6;++c) acc[a][c] = 0.f;

    const int e_st = tid >> 2;
    const int kk0  = (tid & 3) * 8;

    for (int c = 0; c < 3; ++c){
        __syncthreads();
        {
            const float4* src = (const float4*)(W + (size_t)c*BK*FF);
            float4* dst = (float4*)&Ws[0][0];
            dst[tid      ] = src[tid      ];
            dst[tid + 256] = src[tid + 256];
            dst[tid + 512] = src[tid + 512];
        }
        {
            const float* rp = nodes + (size_t)(r0 + e_st)*FF + c*BK;
            *(float4*)&Xs[e_st][kk0    ] = *(const float4*)(rp + kk0);
            *(float4*)&Xs[e_st][kk0 + 4] = *(const float4*)(rp + kk0 + 4);
        }
        __syncthreads();
        #pragma unroll 4
        for (int kk = 0; kk < BK; ++kk){
            float2 w01 = *(const float2*)&Ws[kk][6*tx    ];
            float2 w23 = *(const float2*)&Ws[kk][6*tx + 2];
            float2 w45 = *(const float2*)&Ws[kk][6*tx + 4];
            float xv[4];
            #pragma unroll
            for (int ei=0; ei<4; ++ei) xv[ei] = Xs[ty + 16*ei][kk];
            #pragma unroll
            for (int ei=0; ei<4; ++ei){
                acc[ei][0] += xv[ei]*w01.x;  acc[ei][1] += xv[ei]*w01.y;
                acc[ei][2] += xv[ei]*w23.x;  acc[ei][3] += xv[ei]*w23.y;
                acc[ei][4] += xv[ei]*w45.x;  acc[ei][5] += xv[ei]*w45.y;
            }
        }
    }

    #pragma unroll
    for (int ei = 0; ei < 4; ++ei){
        const int row = r0 + ty + 16*ei;
        float* __restrict__ orow = out + (size_t)row*FF + 6*tx;
        #pragma unroll
        for (int jj=0; jj<6; ++jj) orow[jj] = acc[ei][jj];
    }
}

// ---------------- Kernel 1: edge messages (K=32 GEMM + gather-add epilogue) ----
__global__ __launch_bounds__(256) void edge_msg2_kernel(
    const float* __restrict__ P1, const float* __restrict__ P2,
    const float* __restrict__ ef,
    const int*  __restrict__ edges, const float* __restrict__ ew,
    const float* __restrict__ Wm, const float* __restrict__ bm,
    const float* __restrict__ gm, const float* __restrict__ betam,
    float* __restrict__ wm_out)
{
    const int bid = blockIdx.x;
    const int tid = threadIdx.x;
    const int tx  = tid & 15;
    const int ty  = tid >> 4;
    const int be0 = bid * TE;
    const int b   = be0 >> 14;

    __shared__ float Xs[TE][BK+4];
    __shared__ float Ws[BK][FF];
    __shared__ int   eidx[TE*2];
    __shared__ float ewS[TE];
    __shared__ float bmS[FF], gmS[FF], betamS[FF];

    if (tid < TE*2){
        int v = edges[(size_t)be0*2 + tid];
        if (!((unsigned)v < 1024u)) v = (int)__int_as_float(v);
        eidx[tid] = min(max(v, 0), NN-1);
    }
    if (tid < TE) ewS[tid] = ew[be0 + tid];
    if (tid < FF){ bmS[tid] = bm[tid]; gmS[tid] = gm[tid]; betamS[tid] = betam[tid]; }

    float acc[4][6];
    #pragma unroll
    for (int a=0;a<4;++a)
        #pragma unroll
        for (int c=0;c<6;++c) acc[a][c] = 0.f;

    const int e_st = tid >> 2;
    const int kk0  = (tid & 3) * 8;

    // ---- single K=32 chunk: ef @ Wm[192:224] ----
    {
        const float4* src = (const float4*)(Wm + (size_t)KX*FF);
        float4* dst = (float4*)&Ws[0][0];
        dst[tid      ] = src[tid      ];
        dst[tid + 256] = src[tid + 256];
        dst[tid + 512] = src[tid + 512];
    }
    {
        const float* rp = ef + (size_t)(be0 + e_st)*FE;
        *(float4*)&Xs[e_st][kk0    ] = *(const float4*)(rp + kk0);
        *(float4*)&Xs[e_st][kk0 + 4] = *(const float4*)(rp + kk0 + 4);
    }
    __syncthreads();
    #pragma unroll 4
    for (int kk = 0; kk < BK; ++kk){
        float2 w01 = *(const float2*)&Ws[kk][6*tx    ];
        float2 w23 = *(const float2*)&Ws[kk][6*tx + 2];
        float2 w45 = *(const float2*)&Ws[kk][6*tx + 4];
        float xv[4];
        #pragma unroll
        for (int ei=0; ei<4; ++ei) xv[ei] = Xs[ty + 16*ei][kk];
        #pragma unroll
        for (int ei=0; ei<4; ++ei){
            acc[ei][0] += xv[ei]*w01.x;  acc[ei][1] += xv[ei]*w01.y;
            acc[ei][2] += xv[ei]*w23.x;  acc[ei][3] += xv[ei]*w23.y;
            acc[ei][4] += xv[ei]*w45.x;  acc[ei][5] += xv[ei]*w45.y;
        }
    }

    // ---- prefetch node-projection gathers for all 4 rows (hide L2 latency) ----
    float add[4][6];
    #pragma unroll
    for (int ei = 0; ei < 4; ++ei){
        const int el = ty + 16*ei;
        const int sn = eidx[2*el];
        const int dn = eidx[2*el+1];
        const float2* p1 = (const float2*)(P1 + (size_t)(b*NN + sn)*FF + 6*tx);
        const float2* p2 = (const float2*)(P2 + (size_t)(b*NN + dn)*FF + 6*tx);
        const float2 a0 = p1[0], a1 = p1[1], a2 = p1[2];
        const float2 b0 = p2[0], b1 = p2[1], b2 = p2[2];
        add[ei][0] = a0.x + b0.x;  add[ei][1] = a0.y + b0.y;
        add[ei][2] = a1.x + b1.x;  add[ei][3] = a1.y + b1.y;
        add[ei][4] = a2.x + b2.x;  add[ei][5] = a2.y + b2.y;
    }

    #pragma unroll
    for (int ei = 0; ei < 4; ++ei){
        const int el = ty + 16*ei;
        float h[6]; float psum = 0.f;
        #pragma unroll
        for (int jj=0; jj<6; ++jj){
            h[jj] = gelu_erf(acc[ei][jj] + add[ei][jj] + bmS[6*tx + jj]);
            psum += h[jj];
        }
        #pragma unroll
        for (int m=1; m<16; m<<=1) psum += __shfl_xor(psum, m, 16);
        const float mu = psum * (1.f/FF);
        float vsum = 0.f;
        #pragma unroll
        for (int jj=0; jj<6; ++jj){ float d = h[jj]-mu; vsum += d*d; }
        #pragma unroll
        for (int m=1; m<16; m<<=1) vsum += __shfl_xor(vsum, m, 16);
        const float rstd = rsqrtf(vsum*(1.f/FF) + 1e-3f);

        const float w = ewS[el];
        float* __restrict__ wrow = wm_out + (size_t)(be0 + el)*FF + 6*tx;
        #pragma unroll
        for (int jj=0; jj<6; ++jj)
            wrow[jj] = ((h[jj]-mu)*rstd*gmS[6*tx+jj] + betamS[6*tx+jj]) * w;
    }
}

// ---------------- Kernel 1b: bucket gather -> agg ----------------
// R15: bucket addressing (beg = bn*SLOTS) + LDS prefetch of edge ids and
// coefficients — removes the elist->row dependent-load chain so the row
// loads pipeline (one memory level per iteration instead of two).
__global__ __launch_bounds__(96) void gather_kernel(
    const float* __restrict__ wm_out, const float* __restrict__ ed,
    const int* __restrict__ elist, const int* __restrict__ cnt,
    float* __restrict__ agg)
{
    const int bn = blockIdx.x;       // b*N + n
    const int t  = threadIdx.x;      // 96
    const int num = min(cnt[bn], SLOTS);
    __shared__ int   eS[SLOTS];
    __shared__ float cS[SLOTS];
    if (t < num){
        const int be = elist[bn*SLOTS + t];
        eS[t] = be;
        cS[t] = ed[2*(size_t)be + 1];
    }
    __syncthreads();
    float sum = 0.f;
    for (int i = 0; i < num; ++i)
        sum += wm_out[(size_t)eS[i]*FF + t] * cS[i];
    agg[(size_t)bn*FF + t] = sum;
}

// ---------------- Kernel 2: QKVG projections (tiled GEMM) ----------------
// 64-row tiles, scalar FMA loop. K (m==1) written f16 for attn's
// v_dot2_f32_f16 path (R8).
__global__ __launch_bounds__(256) void qkvg_kernel(
    const float* __restrict__ nodes, const float* __restrict__ agg,
    const float* __restrict__ Wq, const float* __restrict__ bq,
    const float* __restrict__ Wk, const float* __restrict__ bk,
    const float* __restrict__ Wv, const float* __restrict__ bv,
    const float* __restrict__ Wg, const float* __restrict__ bg,
    float* __restrict__ qo, _Float16* __restrict__ ko_h,
    float* __restrict__ vo, float* __restrict__ go)
{
    const int rt  = blockIdx.x;          // 128 row tiles
    const int m   = blockIdx.y;          // 0..3
    const int tid = threadIdx.x;
    const int tx  = tid & 15;
    const int ty  = tid >> 4;
    const int r0  = rt * TE;

    const float* W    = (m==0)?Wq:(m==1)?Wk:(m==2)?Wv:Wg;
    const float* bias = (m==0)?bq:(m==1)?bk:(m==2)?bv:bg;
    float* out        = (m==0)?qo:(m==2)?vo:go;   // m==1 -> ko_h (f16 path)

    __shared__ float Xs[TE][BK+4];
    __shared__ float Ws[BK][FF];
    __shared__ float bS[FF];
    if (tid < FF) bS[tid] = bias[tid];

    float acc[4][6];
    #pragma unroll
    for (int a=0;a<4;++a)
        #pragma unroll
        for (int c=0;c<6;++c) acc[a][c] = 0.f;

    const int e_st = tid >> 2;
    const int kk0  = (tid & 3) * 8;

    for (int c = 0; c < 6; ++c){
        __syncthreads();
        {
            const float4* src = (const float4*)(W + (size_t)c*BK*FF);
            float4* dst = (float4*)&Ws[0][0];
            dst[tid      ] = src[tid      ];
            dst[tid + 256] = src[tid + 256];
            dst[tid + 512] = src[tid + 512];
        }
        {
            const float* rp = (c < 3)
                ? nodes + (size_t)(r0 + e_st)*FF + c*BK
                : agg   + (size_t)(r0 + e_st)*FF + (c-3)*BK;
            *(float4*)&Xs[e_st][kk0    ] = *(const float4*)(rp + kk0);
            *(float4*)&Xs[e_st][kk0 + 4] = *(const float4*)(rp + kk0 + 4);
        }
        __syncthreads();
        #pragma unroll 4
        for (int kk = 0; kk < BK; ++kk){
            float2 w01 = *(const float2*)&Ws[kk][6*tx    ];
            float2 w23 = *(const float2*)&Ws[kk][6*tx + 2];
            float2 w45 = *(const float2*)&Ws[kk][6*tx + 4];
            float xv[4];
            #pragma unroll
            for (int ei=0; ei<4; ++ei) xv[ei] = Xs[ty + 16*ei][kk];
            #pragma unroll
            for (int ei=0; ei<4; ++ei){
                acc[ei][0] += xv[ei]*w01.x;  acc[ei][1] += xv[ei]*w01.y;
                acc[ei][2] += xv[ei]*w23.x;  acc[ei][3] += xv[ei]*w23.y;
                acc[ei][4] += xv[ei]*w45.x;  acc[ei][5] += xv[ei]*w45.y;
            }
        }
    }

    if (m == 1){
        #pragma unroll
        for (int ei = 0; ei < 4; ++ei){
            const int row = r0 + ty + 16*ei;
            _Float16* __restrict__ orow = ko_h + (size_t)row*FF + 6*tx;
            #pragma unroll
            for (int jj=0; jj<6; ++jj) orow[jj] = (_Float16)(acc[ei][jj] + bS[6*tx + jj]);
        }
    } else {
        #pragma unroll
        for (int ei = 0; ei < 4; ++ei){
            const int row = r0 + ty + 16*ei;
            float* __restrict__ orow = out + (size_t)row*FF + 6*tx;
            #pragma unroll
            for (int jj=0; jj<6; ++jj) orow[jj] = acc[ei][jj] + bS[6*tx + jj];
        }
    }
}

// ---------------- Kernel 3: gated attention (LDS-staged flash) ----------
// block = 256 thr = 4 waves per (b, h, 64-row q-tile). R2 lane decomp
// (1 q-row/lane, 16 rows x 4 key-streams) + exp2 rebase + fdot2 QK (R9)
// + -m-seeded dot chain + max3 group max (R10) + pk_fma PV (R11: 67.3 µs,
// VGPR 32, occ 47%) + single 8 KB LDS buffer with register prefetch.
// ~16-17 issue slots per (key,lane) — near the floor for this inst mix.
// att MAY alias g: final phase reads g then writes att from same thread.
__global__ __launch_bounds__(256) void attn_kernel(
    const float* __restrict__ q, const _Float16* __restrict__ kh,
    const float* __restrict__ v, const float* g,
    float* att)
{
    const int blk = blockIdx.x;
    const int qt = blk & 15;              // N/64 = 16 tiles
    const int h  = (blk >> 4) % NH;
    const int b  = blk / (16*NH);
    const int tid  = threadIdx.x;
    const int lane = tid & 63;
    const int w    = tid >> 6;            // wave id 0..3
    const int r    = lane & 15;           // row within wave
    const int s    = lane >> 4;           // key stream 0..3
    const int qrow = qt*64 + w*16 + r;
    const size_t base = (size_t)(b*NN)*FF + h*DD;

    __shared__ _Float16 Ks[128][8];       // 16 B rows (2 KB): 1 b128 = whole K row
    __shared__ float    Vs[128][12];      // 48 B rows (6 KB), conflict-free

    // Q -> f16 pairs, pre-scaled by log2(e)/sqrt(8) for the exp2 softmax
    h2 qh[4];
    {
        const float* qp = q + base + (size_t)qrow*FF;
        #pragma unroll
        for (int i=0;i<4;++i){
            qh[i][0] = (_Float16)(qp[2*i  ] * 0.51010300101462254f);
            qh[i][1] = (_Float16)(qp[2*i+1] * 0.51010300101462254f);
        }
    }

    // mneg = -m (running max, log2 domain), m starts at 0 (R10).
    float mneg = 0.f, l = 0.f;
    f2 o01 = (f2){0.f,0.f}, o23 = (f2){0.f,0.f};
    f2 o45 = (f2){0.f,0.f}, o67 = (f2){0.f,0.f};

    const int skey  = tid >> 1;           // staging: 2 threads per key
    const int half8 = (tid & 1) * 4;      // K: halfs 0-3 / 4-7 ; V: floats 0-3 / 4-7

    // prologue: fetch chunk 0 into regs (K row = 8 B per thread, V = 16 B)
    float2 kreg = *(const float2*)(kh + base + (size_t)skey*FF + half8);
    float4 vreg = *(const float4*)(v  + base + (size_t)skey*FF + half8);

    for (int t = 0; t < 8; ++t){
        // write staged regs (waits vmcnt for kreg/vreg only)
        *(float2*)&Ks[skey][half8] = kreg;
        *(float4*)&Vs[skey][half8] = vreg;
        __syncthreads();
        // issue next chunk's loads NOW; latency hides under compute below
        if (t < 7){
            kreg = *(const float2*)(kh + base + (size_t)((t+1)*128 + skey)*FF + half8);
            vreg = *(const float4*)(v  + base + (size_t)((t+1)*128 + skey)*FF + half8);
        }
        #pragma unroll
        for (int gidx = 0; gidx < 4; ++gidx){
            // pass 1: 8 score dots, chain seeded with -m (already subtracted)
            float sc[8];
            #pragma unroll
            for (int jj = 0; jj < 8; ++jj){
                const int key = 32*gidx + 4*jj + s;
                float4 kraw = *(const float4*)&Ks[key][0];   // 8 halfs
                const h2* kp = (const h2*)&kraw;
                sc[jj] = fdot2(qh[3], kp[3],
                         fdot2(qh[2], kp[2],
                         fdot2(qh[1], kp[1],
                         fdot2(qh[0], kp[0], mneg))));
            }
            // group max via max3-shaped nests (v_max3_f32) + rare rescale
            const float t0 = fmaxf(fmaxf(sc[0], sc[1]), sc[2]);
            const float t1 = fmaxf(fmaxf(sc[3], sc[4]), sc[5]);
            const float t2 = fmaxf(fmaxf(sc[6], sc[7]), t0);
            const float gmax = fmaxf(t1, t2);     // = max(sc[0..7]) (rel. to m)
            if (gmax > 11.5f){
                const float c = EXP2(-gmax);
                l *= c;
                o01[0]*=c; o01[1]*=c; o23[0]*=c; o23[1]*=c;
                o45[0]*=c; o45[1]*=c; o67[0]*=c; o67[1]*=c;
                mneg -= gmax;
                #pragma unroll
                for (int jj=0;jj<8;++jj) sc[jj] -= gmax;
            }
            // pass 2: exp2 + packed PV accumulate (v_pk_fma_f32)
            #pragma unroll
            for (int jj = 0; jj < 8; ++jj){
                const int key = 32*gidx + 4*jj + s;
                float4 v0 = *(const float4*)&Vs[key][0];
                float4 v1 = *(const float4*)&Vs[key][4];
                const f2* va = (const f2*)&v0;
                const f2* vb = (const f2*)&v1;
                const float p = EXP2(sc[jj]);
                l += p;
                f2 p2 = (f2){p, p};
                pk_fma(o01, p2, va[0]);
                pk_fma(o23, p2, va[1]);
                pk_fma(o45, p2, vb[0]);
                pk_fma(o67, p2, vb[1]);
            }
        }
        if (t < 7) __syncthreads();       // all reads done before overwrite
    }

    // unpack pairs for the cross-stream merge
    float o[DD];
    o[0]=o01[0]; o[1]=o01[1]; o[2]=o23[0]; o[3]=o23[1];
    o[4]=o45[0]; o[5]=o45[1]; o[6]=o67[0]; o[7]=o67[1];

    // merge the 4 key-stream partials per row (lanes r, r+16, r+32, r+48)
    float m = -mneg;
    #pragma unroll
    for (int mask = 16; mask <= 32; mask <<= 1){
        const float m2 = __shfl_xor(m, mask);
        const float l2 = __shfl_xor(l, mask);
        float o2[DD];
        #pragma unroll
        for (int i=0;i<DD;++i) o2[i] = __shfl_xor(o[i], mask);
        const float M  = fmaxf(m, m2);
        const float c1 = EXP2(m - M);
        const float c2 = EXP2(m2 - M);
        l = l*c1 + l2*c2;
        #pragma unroll
        for (int i=0;i<DD;++i) o[i] = o[i]*c1 + o2[i]*c2;
        m = M;
    }

    if (s == 0){
        const float inv = 1.f / l;
        const float* gp = g + base + (size_t)qrow*FF;
        float* ap = att + base + (size_t)qrow*FF;
        #pragma unroll
        for (int i=0;i<DD;++i){
            const float gate = 1.f/(1.f + __expf(-gp[i]));
            ap[i] = o[i]*inv*gate;
        }
    }
}

// ---------------- Kernel 4: output projection (tiled GEMM + GELU + LN) ----
// TO=32-row tiles -> 256 blocks (1/CU; 128 was half-idle). 2 rows/thread.
__global__ __launch_bounds__(256) void out_kernel(
    const float* __restrict__ att, const float* __restrict__ Wo, const float* __restrict__ bo,
    const float* __restrict__ gu, const float* __restrict__ betau,
    float* __restrict__ out0)
{
    const int rt  = blockIdx.x;          // 256 row tiles of 32
    const int tid = threadIdx.x;
    const int tx  = tid & 15;
    const int ty  = tid >> 4;
    const int r0  = rt * TO;

    __shared__ float Xs[TO][BK+4];
    __shared__ float Ws[BK][FF];
    __shared__ float boS[FF], guS[FF], beS[FF];
    if (tid < FF){ boS[tid] = bo[tid]; guS[tid] = gu[tid]; beS[tid] = betau[tid]; }

    float acc[2][6];
    #pragma unroll
    for (int a=0;a<2;++a)
        #pragma unroll
        for (int c=0;c<6;++c) acc[a][c] = 0.f;

    const int e_st = tid >> 3;           // 0..31: row within tile
    const int kk0  = (tid & 7) * 4;      // 0..28: 4 floats per thread

    for (int c = 0; c < 3; ++c){
        __syncthreads();
        {
            const float4* src = (const float4*)(Wo + (size_t)c*BK*FF);
            float4* dst = (float4*)&Ws[0][0];
            dst[tid      ] = src[tid      ];
            dst[tid + 256] = src[tid + 256];
            dst[tid + 512] = src[tid + 512];
        }
        {
            const float* rp = att + (size_t)(r0 + e_st)*FF + c*BK;
            *(float4*)&Xs[e_st][kk0] = *(const float4*)(rp + kk0);
        }
        __syncthreads();
        #pragma unroll 4
        for (int kk = 0; kk < BK; ++kk){
            float2 w01 = *(const float2*)&Ws[kk][6*tx    ];
            float2 w23 = *(const float2*)&Ws[kk][6*tx + 2];
            float2 w45 = *(const float2*)&Ws[kk][6*tx + 4];
            float xv[2];
            xv[0] = Xs[ty     ][kk];
            xv[1] = Xs[ty + 16][kk];
            #pragma unroll
            for (int ei=0; ei<2; ++ei){
                acc[ei][0] += xv[ei]*w01.x;  acc[ei][1] += xv[ei]*w01.y;
                acc[ei][2] += xv[ei]*w23.x;  acc[ei][3] += xv[ei]*w23.y;
                acc[ei][4] += xv[ei]*w45.x;  acc[ei][5] += xv[ei]*w45.y;
            }
        }
    }

    #pragma unroll
    for (int ei = 0; ei < 2; ++ei){
        const int row = r0 + ty + 16*ei;
        float h[6]; float psum = 0.f;
        #pragma unroll
        for (int jj=0; jj<6; ++jj){
            h[jj] = gelu_erf(acc[ei][jj] + boS[6*tx + jj]);
            psum += h[jj];
        }
        #pragma unroll
        for (int m=1; m<16; m<<=1) psum += __shfl_xor(psum, m, 16);
        const float mu = psum * (1.f/FF);
        float vsum = 0.f;
        #pragma unroll
        for (int jj=0; jj<6; ++jj){ float d = h[jj]-mu; vsum += d*d; }
        #pragma unroll
        for (int m=1; m<16; m<<=1) vsum += __shfl_xor(vsum, m, 16);
        const float rstd = rsqrtf(vsum*(1.f/FF) + 1e-3f);
        float* __restrict__ orow = out0 + (size_t)row*FF + 6*tx;
        #pragma unroll
        for (int jj=0; jj<6; ++jj)
            orow[jj] = (h[jj]-mu)*rstd*guS[6*tx+jj] + beS[6*tx+jj];
    }
}

extern "C" void kernel_launch(void* const* d_in, const int* in_sizes, int n_in,
                              void* d_out, int out_size, void* d_ws, size_t ws_size,
                              hipStream_t stream) {
    // ---- adaptive input mapping by element count (dict-order tiebreak) ----
    int i_nodes=-1, i_ef=-1, i_edges=-1, i_ed=-1, i_ew=-1, i_Wm=-1, i_Wo=-1;
    int i_W4[4]; int nW4=0;
    int i_v96[10]; int nv96=0;
    for (int i = 0; i < n_in; ++i){
        const int s = in_sizes[i];
        if      (s == 786432)  i_nodes = i;
        else if (s == 4194304) i_ef = i;
        else if (s == 262144)  { if (i_edges < 0) i_edges = i; else i_ed = i; }
        else if (s == 131072)  i_ew = i;
        else if (s == 21504)   i_Wm = i;
        else if (s == 18432)   { if (nW4 < 4) i_W4[nW4++] = i; }
        else if (s == 9216)    i_Wo = i;
        else if (s == 96)      { if (nv96 < 10) i_v96[nv96++] = i; }
    }
    const float* nodes = (const float*)d_in[i_nodes];
    const float* ef    = (const float*)d_in[i_ef];
    const int*   edges = (const int*)d_in[i_edges];
    const float* ew    = (const float*)d_in[i_ew];
    const float* ed    = (const float*)d_in[i_ed];
    const float* Wm = (const float*)d_in[i_Wm];
    const float* Wq = (const float*)d_in[i_W4[0]];
    const float* Wk = (const float*)d_in[i_W4[1]];
    const float* Wv = (const float*)d_in[i_W4[2]];
    const float* Wg = (const float*)d_in[i_W4[3]];
    const float* Wo = (const float*)d_in[i_Wo];
    const float* bm    = (const float*)d_in[i_v96[0]];
    const float* gm    = (const float*)d_in[i_v96[1]];
    const float* betam = (const float*)d_in[i_v96[2]];
    const float* bq    = (const float*)d_in[i_v96[3]];
    const float* bk    = (const float*)d_in[i_v96[4]];
    const float* bv    = (const float*)d_in[i_v96[5]];
    const float* bg    = (const float*)d_in[i_v96[6]];
    const float* bo    = (const float*)d_in[i_v96[7]];
    const float* gu    = (const float*)d_in[i_v96[8]];
    const float* betau = (const float*)d_in[i_v96[9]];

    // ---- output layout: fp32, reference return order ----
    float* outp = (float*)d_out;
    const size_t ROWS  = (size_t)BB*NN*FF;     // 786432
    const size_t WMSZ  = (size_t)BB*EE*FF;     // 12582912
    const size_t NE2   = (size_t)BB*EE*2;      // 262144
    const size_t NW    = (size_t)BB*EE;        // 131072
    float* out_un    = outp;
    float* out_wm    = outp + ROWS;
    float* out_edges = outp + ROWS + WMSZ;
    float* out_ew    = outp + ROWS + WMSZ + NE2;
    float* out_ed    = outp + ROWS + WMSZ + NE2 + NW;

    // ---- workspace layout ----
    float* ws  = (float*)d_ws;
    float* agg = ws;
    float* qo  = ws + 1*ROWS;
    _Float16* ko_h = (_Float16*)(ws + 2*ROWS);   // K stored f16 (fdot2 path)
    float* vo  = ws + 3*ROWS;
    float* go  = ws + 4*ROWS;       // att aliases go (safe: same-thread RMW)
    float* att = go;
    // P1/P2 alias qo/ko regions: dead before qkvg_kernel writes them
    float* P1  = qo;
    float* P2  = ws + 2*ROWS;
    // elist buckets (B*N*SLOTS ints = 2 MB) alias the vo region: written by
    // scatter, read by gather — both BEFORE qkvg writes vo. cnt is tiny.
    int* elist = (int*)vo;                    // B*N*SLOTS
    int* cnt   = (int*)(ws + 5*ROWS);         // B*N

    hipMemsetAsync(cnt, 0, BB*NN*sizeof(int), stream);

    // bucket append + passthrough copies (replaces hist/scan/scatter — R15)
    const int npass = (int)(NE2 + NW + NE2);
    scatter_kernel<<<(npass+255)/256, 256, 0, stream>>>(edges, cnt, elist,
                                               ew, ed, out_edges, out_ew, out_ed);

    // node projections (P1 = nodes@Wm1, P2 = nodes@Wm2) — 64-row tiles
    dim3 npgrid((BB*NN)/TE, 2);
    node_proj_kernel<<<npgrid, 256, 0, stream>>>(nodes, Wm, P1, P2);

    // edge messages: K=32 GEMM + gather-add epilogue (writes wm only)
    edge_msg2_kernel<<<(BB*EE)/TE, 256, 0, stream>>>(P1, P2, ef, edges, ew,
                                               Wm, bm, gm, betam, out_wm);
    // bucket gather -> agg
    gather_kernel<<<BB*NN, 96, 0, stream>>>(out_wm, ed, elist, cnt, agg);

    // QKVG projections — 64-row tiles
    dim3 qgrid((BB*NN)/TE, 4);
    qkvg_kernel<<<qgrid, 256, 0, stream>>>(nodes, agg, Wq, bq, Wk, bk, Wv, bv,
                                           Wg, bg, qo, ko_h, vo, go);
    attn_kernel<<<BB*NH*16, 256, 0, stream>>>(qo, ko_h, vo, go, att);
    // output projection — 32-row tiles (256 blocks)
    out_kernel<<<(BB*NN)/TO, 256, 0, stream>>>(att, Wo, bo, gu, betau, out_un);
}